// Round 1
// baseline (1841.760 us; speedup 1.0000x reference)
//
#include <hip/hip_runtime.h>

// Problem constants
#define N 65536     // B*H*W rows
#define D 256
#define K 1024
#define BETA 0.25f
#define GAMMA 0.9f
#define EPS 1e-5f

// Workspace layout (bytes)
#define OFF_INDICES 0                 // N int
#define OFF_PERM    262144            // N int
#define OFF_COUNTS  524288            // K int
#define OFF_OFFSETS 528384            // K int
#define OFF_CURSOR  532480            // K int
#define OFF_SMOOTH  536576            // K float
#define OFF_LOSS    540672            // 1 float (padded)
#define OFF_CNORM   540736            // K float
#define OFF_CBT     544832            // K*D float (1 MB)

// ---------------------------------------------------------------------------
// Transpose codebook [D][K] -> cbT [K][D] for coalesced quantize reads
__global__ __launch_bounds__(256) void transpose_cb(const float* __restrict__ cb,
                                                    float* __restrict__ cbT) {
    __shared__ float tile[32][33];
    const int tx = threadIdx.x & 31;
    const int ty = threadIdx.x >> 5;       // 0..7
    const int k0 = blockIdx.x * 32;        // 32 blocks over K
    const int d0 = blockIdx.y * 32;        // 8 blocks over D
#pragma unroll
    for (int i = 0; i < 4; ++i)
        tile[ty + 8 * i][tx] = cb[(d0 + ty + 8 * i) * K + k0 + tx];
    __syncthreads();
#pragma unroll
    for (int i = 0; i < 4; ++i)
        cbT[(k0 + ty + 8 * i) * D + d0 + tx] = tile[tx][ty + 8 * i];
}

// cnorm[k] = sum_d cb[d][k]^2
__global__ __launch_bounds__(256) void cnorm_kernel(const float* __restrict__ cb,
                                                    float* __restrict__ cnorm) {
    const int k = blockIdx.x * 256 + threadIdx.x;
    float acc = 0.f;
    for (int d = 0; d < D; ++d) {
        float v = cb[d * K + k];
        acc = fmaf(v, v, acc);
    }
    cnorm[k] = acc;
}

// ---------------------------------------------------------------------------
// Fused GEMM + argmin: for each row n, argmin_k (cnorm[k] - 2 * x_n . cb[:,k])
// Block: 256 threads = 16x16, each 4x4 micro-tile. M-tile 64 rows, N-tile 64
// cols (16 col tiles), D chunked by 64.
__global__ __launch_bounds__(256) void argmin_kernel(const float* __restrict__ x,
                                                     const float* __restrict__ cb,
                                                     const float* __restrict__ cnorm,
                                                     int* __restrict__ indices) {
    __shared__ float As[64 * 68];   // [d][r], stride 68 (pad): b128 reads aligned, 2-way max
    __shared__ float Bs[64 * 64];   // [d][c]
    __shared__ float redv[16 * 64];
    __shared__ int   redi[16 * 64];

    const int tid = threadIdx.x;
    const int tr = tid >> 4;        // 0..15 row group
    const int tc = tid & 15;        // 0..15 col group
    const int r0 = blockIdx.x * 64;

    float minv[4];
    int mini[4];
#pragma unroll
    for (int i = 0; i < 4; ++i) { minv[i] = 3.4e38f; mini[i] = 0; }

    for (int ct = 0; ct < 16; ++ct) {
        float acc[4][4] = {};
        const int c0 = ct * 64;
        for (int ch = 0; ch < 4; ++ch) {
            const int d0 = ch * 64;
            // Stage A chunk transposed: As[d][r] = x[r0+r][d0+d]
#pragma unroll
            for (int p = 0; p < 4; ++p) {
                int id = p * 256 + tid;       // float4 id, 0..1023
                int r = id >> 4;              // 0..63
                int f = id & 15;              // 0..15 -> d = 4f
                float4 v = *(const float4*)&x[(r0 + r) * D + d0 + 4 * f];
                As[(4 * f + 0) * 68 + r] = v.x;
                As[(4 * f + 1) * 68 + r] = v.y;
                As[(4 * f + 2) * 68 + r] = v.z;
                As[(4 * f + 3) * 68 + r] = v.w;
            }
            // Stage B chunk: Bs[d][c] = cb[d0+d][c0+c]
#pragma unroll
            for (int p = 0; p < 4; ++p) {
                int id = p * 256 + tid;
                int d = id >> 4;
                int f = id & 15;
                *(float4*)&Bs[d * 64 + 4 * f] =
                    *(const float4*)&cb[(d0 + d) * K + c0 + 4 * f];
            }
            __syncthreads();
#pragma unroll 8
            for (int d = 0; d < 64; ++d) {
                float4 a = *(const float4*)&As[d * 68 + tr * 4];
                float4 b = *(const float4*)&Bs[d * 64 + tc * 4];
                acc[0][0] = fmaf(a.x, b.x, acc[0][0]);
                acc[0][1] = fmaf(a.x, b.y, acc[0][1]);
                acc[0][2] = fmaf(a.x, b.z, acc[0][2]);
                acc[0][3] = fmaf(a.x, b.w, acc[0][3]);
                acc[1][0] = fmaf(a.y, b.x, acc[1][0]);
                acc[1][1] = fmaf(a.y, b.y, acc[1][1]);
                acc[1][2] = fmaf(a.y, b.z, acc[1][2]);
                acc[1][3] = fmaf(a.y, b.w, acc[1][3]);
                acc[2][0] = fmaf(a.z, b.x, acc[2][0]);
                acc[2][1] = fmaf(a.z, b.y, acc[2][1]);
                acc[2][2] = fmaf(a.z, b.z, acc[2][2]);
                acc[2][3] = fmaf(a.z, b.w, acc[2][3]);
                acc[3][0] = fmaf(a.w, b.x, acc[3][0]);
                acc[3][1] = fmaf(a.w, b.y, acc[3][1]);
                acc[3][2] = fmaf(a.w, b.z, acc[3][2]);
                acc[3][3] = fmaf(a.w, b.w, acc[3][3]);
            }
            __syncthreads();
        }
        // Argmin epilogue over this column tile (ascending k, strict < keeps first)
#pragma unroll
        for (int j = 0; j < 4; ++j) {
            int c = c0 + tc * 4 + j;
            float cn = cnorm[c];
#pragma unroll
            for (int i = 0; i < 4; ++i) {
                float val = fmaf(-2.0f, acc[i][j], cn);
                if (val < minv[i]) { minv[i] = val; mini[i] = c; }
            }
        }
    }
    // Cross-thread (tc) reduction per row; tie -> lower index
#pragma unroll
    for (int i = 0; i < 4; ++i) {
        redv[tc * 64 + tr * 4 + i] = minv[i];
        redi[tc * 64 + tr * 4 + i] = mini[i];
    }
    __syncthreads();
    if (tid < 64) {
        float bv = redv[tid];
        int bi = redi[tid];
#pragma unroll
        for (int t = 1; t < 16; ++t) {
            float v = redv[t * 64 + tid];
            int ix = redi[t * 64 + tid];
            if (v < bv || (v == bv && ix < bi)) { bv = v; bi = ix; }
        }
        indices[r0 + tid] = bi;
    }
}

// ---------------------------------------------------------------------------
// ste (= quantized) + loss partials + cluster histogram
__global__ __launch_bounds__(256) void quantize_kernel(const float* __restrict__ x,
                                                       const float* __restrict__ cbT,
                                                       const int* __restrict__ indices,
                                                       float* __restrict__ ste,
                                                       int* __restrict__ counts,
                                                       float* __restrict__ loss_acc) {
    const int n = blockIdx.x;
    const int d = threadIdx.x;
    const int k = indices[n];
    float q = cbT[k * D + d];
    float xi = x[n * D + d];
    ste[n * D + d] = q;
    float diff = q - xi;
    float s = diff * diff;
    // wave reduce (64) then block reduce (4 waves)
#pragma unroll
    for (int off = 32; off >= 1; off >>= 1) s += __shfl_down(s, off, 64);
    __shared__ float red[4];
    const int wave = threadIdx.x >> 6;
    const int lane = threadIdx.x & 63;
    if (lane == 0) red[wave] = s;
    __syncthreads();
    if (threadIdx.x == 0) {
        float tot = red[0] + red[1] + red[2] + red[3];
        atomicAdd(loss_acc, tot);
        atomicAdd(&counts[k], 1);
    }
}

// ---------------------------------------------------------------------------
// Single block: EMA cluster stats, perplexity, loss finalize, prefix-sum, cursor
__global__ __launch_bounds__(1024) void finalize_kernel(const int* __restrict__ counts,
                                                        const float* __restrict__ ema_c,
                                                        const int* __restrict__ counter,
                                                        const float* __restrict__ loss_acc,
                                                        float* __restrict__ out_perp,
                                                        float* __restrict__ out_loss,
                                                        int* __restrict__ offsets,
                                                        int* __restrict__ cursor,
                                                        float* __restrict__ smoothed) {
    const int k = threadIdx.x;
    __shared__ float fred[1024];
    __shared__ int scan[1024];
    __shared__ float nsum_s;

    const int c = counts[k];
    const float bias = 1.0f - powf(GAMMA, (float)counter[0]);
    const float hid = fmaf(ema_c[k], GAMMA, (float)c * (1.0f - GAMMA));
    const float avg = hid / bias;

    // n = sum(avg_cs)
    fred[k] = avg;
    __syncthreads();
    for (int s = 512; s >= 1; s >>= 1) {
        if (k < s) fred[k] += fred[k + s];
        __syncthreads();
    }
    if (k == 0) nsum_s = fred[0];
    __syncthreads();
    const float nsum = nsum_s;

    // entropy
    float p = (float)c * (1.0f / (float)N);
    fred[k] = p * logf(p + 1e-10f);
    __syncthreads();
    for (int s = 512; s >= 1; s >>= 1) {
        if (k < s) fred[k] += fred[k + s];
        __syncthreads();
    }

    // inclusive scan of counts -> exclusive offsets
    scan[k] = c;
    __syncthreads();
    for (int s = 1; s < 1024; s <<= 1) {
        int v = (k >= s) ? scan[k - s] : 0;
        __syncthreads();
        scan[k] += v;
        __syncthreads();
    }
    const int excl = scan[k] - c;
    offsets[k] = excl;
    cursor[k] = excl;

    smoothed[k] = (avg + EPS) / (nsum + (float)K * EPS) * nsum;

    if (k == 0) {
        out_perp[0] = expf(-fred[0]);
        out_loss[0] = BETA * loss_acc[0] * (1.0f / ((float)N * (float)D));
    }
}

// Build permutation: rows grouped by cluster
__global__ __launch_bounds__(256) void scatter_kernel(const int* __restrict__ indices,
                                                      int* __restrict__ cursor,
                                                      int* __restrict__ perm) {
    const int n = blockIdx.x * 256 + threadIdx.x;
    const int k = indices[n];
    const int pos = atomicAdd(&cursor[k], 1);
    perm[pos] = n;
}

// ---------------------------------------------------------------------------
// dw[:,k] = sum of member rows; new_codebook = ((ema_dw*g + dw*(1-g))/bias)/smoothed
__global__ __launch_bounds__(256) void dw_codebook_kernel(const float* __restrict__ x,
                                                          const int* __restrict__ perm,
                                                          const int* __restrict__ offsets,
                                                          const int* __restrict__ counts,
                                                          const float* __restrict__ ema_dw,
                                                          const float* __restrict__ smoothed,
                                                          const int* __restrict__ counter,
                                                          float* __restrict__ out_cb) {
    const int k = blockIdx.x;
    const int d = threadIdx.x;
    const int off = offsets[k];
    const int cnt = counts[k];
    float acc = 0.f;
    int i = 0;
    for (; i + 4 <= cnt; i += 4) {
        int n0 = perm[off + i + 0];
        int n1 = perm[off + i + 1];
        int n2 = perm[off + i + 2];
        int n3 = perm[off + i + 3];
        acc += x[n0 * D + d] + x[n1 * D + d] + x[n2 * D + d] + x[n3 * D + d];
    }
    for (; i < cnt; ++i) acc += x[perm[off + i] * D + d];
    const float bias = 1.0f - powf(GAMMA, (float)counter[0]);
    const float hid = fmaf(ema_dw[d * K + k], GAMMA, acc * (1.0f - GAMMA));
    out_cb[d * K + k] = (hid / bias) / smoothed[k];
}

// ---------------------------------------------------------------------------
extern "C" void kernel_launch(void* const* d_in, const int* in_sizes, int n_in,
                              void* d_out, int out_size, void* d_ws, size_t ws_size,
                              hipStream_t stream) {
    const float* x       = (const float*)d_in[0];  // [N, D]
    const float* cb      = (const float*)d_in[1];  // [D, K]
    const float* ema_c   = (const float*)d_in[2];  // [K]
    const float* ema_dw  = (const float*)d_in[3];  // [D, K]
    const int*   counter = (const int*)d_in[4];

    float* out = (float*)d_out;
    float* ste = out;                        // N*D
    float* out_perp = out + (size_t)N * D;   // 1
    float* out_loss = out_perp + 1;          // 1
    float* out_cb = out_perp + 2;            // D*K

    char* ws = (char*)d_ws;
    int* indices  = (int*)(ws + OFF_INDICES);
    int* perm     = (int*)(ws + OFF_PERM);
    int* counts   = (int*)(ws + OFF_COUNTS);
    int* offsets  = (int*)(ws + OFF_OFFSETS);
    int* cursor   = (int*)(ws + OFF_CURSOR);
    float* smooth = (float*)(ws + OFF_SMOOTH);
    float* lossac = (float*)(ws + OFF_LOSS);
    float* cnorm  = (float*)(ws + OFF_CNORM);
    float* cbT    = (float*)(ws + OFF_CBT);

    // zero counts..loss region (16448 B ends exactly at OFF_CNORM)
    hipMemsetAsync(ws + OFF_COUNTS, 0, OFF_CNORM - OFF_COUNTS, stream);

    transpose_cb<<<dim3(32, 8), 256, 0, stream>>>(cb, cbT);
    cnorm_kernel<<<K / 256, 256, 0, stream>>>(cb, cnorm);
    argmin_kernel<<<N / 64, 256, 0, stream>>>(x, cb, cnorm, indices);
    quantize_kernel<<<N, 256, 0, stream>>>(x, cbT, indices, ste, counts, lossac);
    finalize_kernel<<<1, 1024, 0, stream>>>(counts, ema_c, counter, lossac,
                                            out_perp, out_loss, offsets, cursor, smooth);
    scatter_kernel<<<N / 256, 256, 0, stream>>>(indices, cursor, perm);
    dw_codebook_kernel<<<K, 256, 0, stream>>>(x, perm, offsets, counts, ema_dw,
                                              smooth, counter, out_cb);
}

// Round 2
// 1014.616 us; speedup vs baseline: 1.8152x; 1.8152x over previous
//
#include <hip/hip_runtime.h>

// Problem constants
#define N 65536     // B*H*W rows
#define D 256
#define K 1024
#define BETA 0.25f
#define GAMMA 0.9f
#define EPS 1e-5f

#define QBLOCKS 512  // quantize kernel grid size (loss partials)

// Workspace layout (bytes)
#define OFF_INDICES 0                 // N int
#define OFF_PERM    262144            // N int
#define OFF_COUNTS  524288            // K int
#define OFF_OFFSETS 528384            // K int
#define OFF_CURSOR  532480            // K int
#define OFF_SMOOTH  536576            // K float
#define OFF_LOSSP   540672            // QBLOCKS floats (2 KB)
#define OFF_CNORM   542720            // K float
#define OFF_CBT     546816            // K*D float (1 MB)

// ---------------------------------------------------------------------------
// Transpose codebook [D][K] -> cbT [K][D] for coalesced quantize reads
__global__ __launch_bounds__(256) void transpose_cb(const float* __restrict__ cb,
                                                    float* __restrict__ cbT) {
    __shared__ float tile[32][33];
    const int tx = threadIdx.x & 31;
    const int ty = threadIdx.x >> 5;       // 0..7
    const int k0 = blockIdx.x * 32;        // 32 blocks over K
    const int d0 = blockIdx.y * 32;        // 8 blocks over D
#pragma unroll
    for (int i = 0; i < 4; ++i)
        tile[ty + 8 * i][tx] = cb[(d0 + ty + 8 * i) * K + k0 + tx];
    __syncthreads();
#pragma unroll
    for (int i = 0; i < 4; ++i)
        cbT[(k0 + ty + 8 * i) * D + d0 + tx] = tile[tx][ty + 8 * i];
}

// cnorm[k] = sum_d cb[d][k]^2
__global__ __launch_bounds__(256) void cnorm_kernel(const float* __restrict__ cb,
                                                    float* __restrict__ cnorm) {
    const int k = blockIdx.x * 256 + threadIdx.x;
    float acc = 0.f;
    for (int d = 0; d < D; ++d) {
        float v = cb[d * K + k];
        acc = fmaf(v, v, acc);
    }
    cnorm[k] = acc;
}

// ---------------------------------------------------------------------------
// Fused GEMM + argmin: for each row n, argmin_k (cnorm[k] - 2 * x_n . cb[:,k])
// Block: 256 threads = 16x16, each 4x4 micro-tile. M-tile 64 rows, N-tile 64
// cols (16 col tiles), D chunked by 64.
__global__ __launch_bounds__(256) void argmin_kernel(const float* __restrict__ x,
                                                     const float* __restrict__ cb,
                                                     const float* __restrict__ cnorm,
                                                     int* __restrict__ indices) {
    __shared__ float As[64 * 68];   // [d][r], stride 68 (pad): b128 reads aligned, 2-way max
    __shared__ float Bs[64 * 64];   // [d][c]
    __shared__ float redv[16 * 64];
    __shared__ int   redi[16 * 64];

    const int tid = threadIdx.x;
    const int tr = tid >> 4;        // 0..15 row group
    const int tc = tid & 15;        // 0..15 col group
    const int r0 = blockIdx.x * 64;

    float minv[4];
    int mini[4];
#pragma unroll
    for (int i = 0; i < 4; ++i) { minv[i] = 3.4e38f; mini[i] = 0; }

    for (int ct = 0; ct < 16; ++ct) {
        float acc[4][4] = {};
        const int c0 = ct * 64;
        for (int ch = 0; ch < 4; ++ch) {
            const int d0 = ch * 64;
            // Stage A chunk transposed: As[d][r] = x[r0+r][d0+d]
#pragma unroll
            for (int p = 0; p < 4; ++p) {
                int id = p * 256 + tid;       // float4 id, 0..1023
                int r = id >> 4;              // 0..63
                int f = id & 15;              // 0..15 -> d = 4f
                float4 v = *(const float4*)&x[(r0 + r) * D + d0 + 4 * f];
                As[(4 * f + 0) * 68 + r] = v.x;
                As[(4 * f + 1) * 68 + r] = v.y;
                As[(4 * f + 2) * 68 + r] = v.z;
                As[(4 * f + 3) * 68 + r] = v.w;
            }
            // Stage B chunk: Bs[d][c] = cb[d0+d][c0+c]
#pragma unroll
            for (int p = 0; p < 4; ++p) {
                int id = p * 256 + tid;
                int d = id >> 4;
                int f = id & 15;
                *(float4*)&Bs[d * 64 + 4 * f] =
                    *(const float4*)&cb[(d0 + d) * K + c0 + 4 * f];
            }
            __syncthreads();
#pragma unroll 8
            for (int d = 0; d < 64; ++d) {
                float4 a = *(const float4*)&As[d * 68 + tr * 4];
                float4 b = *(const float4*)&Bs[d * 64 + tc * 4];
                acc[0][0] = fmaf(a.x, b.x, acc[0][0]);
                acc[0][1] = fmaf(a.x, b.y, acc[0][1]);
                acc[0][2] = fmaf(a.x, b.z, acc[0][2]);
                acc[0][3] = fmaf(a.x, b.w, acc[0][3]);
                acc[1][0] = fmaf(a.y, b.x, acc[1][0]);
                acc[1][1] = fmaf(a.y, b.y, acc[1][1]);
                acc[1][2] = fmaf(a.y, b.z, acc[1][2]);
                acc[1][3] = fmaf(a.y, b.w, acc[1][3]);
                acc[2][0] = fmaf(a.z, b.x, acc[2][0]);
                acc[2][1] = fmaf(a.z, b.y, acc[2][1]);
                acc[2][2] = fmaf(a.z, b.z, acc[2][2]);
                acc[2][3] = fmaf(a.z, b.w, acc[2][3]);
                acc[3][0] = fmaf(a.w, b.x, acc[3][0]);
                acc[3][1] = fmaf(a.w, b.y, acc[3][1]);
                acc[3][2] = fmaf(a.w, b.z, acc[3][2]);
                acc[3][3] = fmaf(a.w, b.w, acc[3][3]);
            }
            __syncthreads();
        }
        // Argmin epilogue over this column tile (ascending k, strict < keeps first)
#pragma unroll
        for (int j = 0; j < 4; ++j) {
            int c = c0 + tc * 4 + j;
            float cn = cnorm[c];
#pragma unroll
            for (int i = 0; i < 4; ++i) {
                float val = fmaf(-2.0f, acc[i][j], cn);
                if (val < minv[i]) { minv[i] = val; mini[i] = c; }
            }
        }
    }
    // Cross-thread (tc) reduction per row; tie -> lower index
#pragma unroll
    for (int i = 0; i < 4; ++i) {
        redv[tc * 64 + tr * 4 + i] = minv[i];
        redi[tc * 64 + tr * 4 + i] = mini[i];
    }
    __syncthreads();
    if (tid < 64) {
        float bv = redv[tid];
        int bi = redi[tid];
#pragma unroll
        for (int t = 1; t < 16; ++t) {
            float v = redv[t * 64 + tid];
            int ix = redi[t * 64 + tid];
            if (v < bv || (v == bv && ix < bi)) { bv = v; bi = ix; }
        }
        indices[r0 + tid] = bi;
    }
}

// ---------------------------------------------------------------------------
// ste (= quantized) + loss partials + cluster histogram.
// One WAVE per row: 64 lanes x float4 covers the 256-float row, coalesced.
// Loss: register accumulate -> wave shuffle reduce -> block reduce -> ONE
// plain store per block (no single-address atomics; R0's 65536-deep atomic
// chain on loss_acc was 12.7 ns/block = 834 us).
__global__ __launch_bounds__(256) void quantize_kernel(const float* __restrict__ x,
                                                       const float* __restrict__ cbT,
                                                       const int* __restrict__ indices,
                                                       float* __restrict__ ste,
                                                       int* __restrict__ counts,
                                                       float* __restrict__ loss_partial) {
    const int lane = threadIdx.x & 63;
    const int wid = (blockIdx.x * 256 + threadIdx.x) >> 6;   // global wave id
    const int nwaves = QBLOCKS * 4;

    float s = 0.f;
    for (int row = wid; row < N; row += nwaves) {
        const int k = indices[row];                 // broadcast load (same addr all lanes)
        float4 q  = *(const float4*)&cbT[k * D + lane * 4];   // L2-resident (1 MB)
        float4 xi = *(const float4*)&x[(size_t)row * D + lane * 4];
        *(float4*)&ste[(size_t)row * D + lane * 4] = q;
        float dx = q.x - xi.x, dy = q.y - xi.y, dz = q.z - xi.z, dw = q.w - xi.w;
        s = fmaf(dx, dx, s); s = fmaf(dy, dy, s);
        s = fmaf(dz, dz, s); s = fmaf(dw, dw, s);
        if (lane == 0) atomicAdd(&counts[k], 1);    // 1024-way spread, ~64/address
    }
    // wave reduce (64 lanes)
#pragma unroll
    for (int off = 32; off >= 1; off >>= 1) s += __shfl_down(s, off, 64);
    __shared__ float red[4];
    if (lane == 0) red[threadIdx.x >> 6] = s;
    __syncthreads();
    if (threadIdx.x == 0)
        loss_partial[blockIdx.x] = red[0] + red[1] + red[2] + red[3];
}

// ---------------------------------------------------------------------------
// Single block: EMA cluster stats, perplexity, loss finalize, prefix-sum, cursor
__global__ __launch_bounds__(1024) void finalize_kernel(const int* __restrict__ counts,
                                                        const float* __restrict__ ema_c,
                                                        const int* __restrict__ counter,
                                                        const float* __restrict__ loss_partial,
                                                        float* __restrict__ out_perp,
                                                        float* __restrict__ out_loss,
                                                        int* __restrict__ offsets,
                                                        int* __restrict__ cursor,
                                                        float* __restrict__ smoothed) {
    const int k = threadIdx.x;
    __shared__ float fred[1024];
    __shared__ int scan[1024];
    __shared__ float nsum_s;
    __shared__ float ent_s;

    const int c = counts[k];
    const float bias = 1.0f - powf(GAMMA, (float)counter[0]);
    const float hid = fmaf(ema_c[k], GAMMA, (float)c * (1.0f - GAMMA));
    const float avg = hid / bias;

    // n = sum(avg_cs)
    fred[k] = avg;
    __syncthreads();
    for (int s = 512; s >= 1; s >>= 1) {
        if (k < s) fred[k] += fred[k + s];
        __syncthreads();
    }
    if (k == 0) nsum_s = fred[0];
    __syncthreads();
    const float nsum = nsum_s;

    // entropy
    float p = (float)c * (1.0f / (float)N);
    fred[k] = p * logf(p + 1e-10f);
    __syncthreads();
    for (int s = 512; s >= 1; s >>= 1) {
        if (k < s) fred[k] += fred[k + s];
        __syncthreads();
    }
    if (k == 0) ent_s = fred[0];
    __syncthreads();

    // loss partial sum (QBLOCKS entries)
    fred[k] = (k < QBLOCKS) ? loss_partial[k] : 0.f;
    __syncthreads();
    for (int s = 512; s >= 1; s >>= 1) {
        if (k < s) fred[k] += fred[k + s];
        __syncthreads();
    }

    // inclusive scan of counts -> exclusive offsets
    scan[k] = c;
    __syncthreads();
    for (int s = 1; s < 1024; s <<= 1) {
        int v = (k >= s) ? scan[k - s] : 0;
        __syncthreads();
        scan[k] += v;
        __syncthreads();
    }
    const int excl = scan[k] - c;
    offsets[k] = excl;
    cursor[k] = excl;

    smoothed[k] = (avg + EPS) / (nsum + (float)K * EPS) * nsum;

    if (k == 0) {
        out_perp[0] = expf(-ent_s);
        out_loss[0] = BETA * fred[0] * (1.0f / ((float)N * (float)D));
    }
}

// Build permutation: rows grouped by cluster
__global__ __launch_bounds__(256) void scatter_kernel(const int* __restrict__ indices,
                                                      int* __restrict__ cursor,
                                                      int* __restrict__ perm) {
    const int n = blockIdx.x * 256 + threadIdx.x;
    const int k = indices[n];
    const int pos = atomicAdd(&cursor[k], 1);
    perm[pos] = n;
}

// ---------------------------------------------------------------------------
// dw[:,k] = sum of member rows; new_codebook = ((ema_dw*g + dw*(1-g))/bias)/smoothed
__global__ __launch_bounds__(256) void dw_codebook_kernel(const float* __restrict__ x,
                                                          const int* __restrict__ perm,
                                                          const int* __restrict__ offsets,
                                                          const int* __restrict__ counts,
                                                          const float* __restrict__ ema_dw,
                                                          const float* __restrict__ smoothed,
                                                          const int* __restrict__ counter,
                                                          float* __restrict__ out_cb) {
    const int k = blockIdx.x;
    const int d = threadIdx.x;
    const int off = offsets[k];
    const int cnt = counts[k];
    float acc = 0.f;
    int i = 0;
    for (; i + 4 <= cnt; i += 4) {
        int n0 = perm[off + i + 0];
        int n1 = perm[off + i + 1];
        int n2 = perm[off + i + 2];
        int n3 = perm[off + i + 3];
        acc += x[n0 * D + d] + x[n1 * D + d] + x[n2 * D + d] + x[n3 * D + d];
    }
    for (; i < cnt; ++i) acc += x[perm[off + i] * D + d];
    const float bias = 1.0f - powf(GAMMA, (float)counter[0]);
    const float hid = fmaf(ema_dw[d * K + k], GAMMA, acc * (1.0f - GAMMA));
    out_cb[d * K + k] = (hid / bias) / smoothed[k];
}

// ---------------------------------------------------------------------------
extern "C" void kernel_launch(void* const* d_in, const int* in_sizes, int n_in,
                              void* d_out, int out_size, void* d_ws, size_t ws_size,
                              hipStream_t stream) {
    const float* x       = (const float*)d_in[0];  // [N, D]
    const float* cb      = (const float*)d_in[1];  // [D, K]
    const float* ema_c   = (const float*)d_in[2];  // [K]
    const float* ema_dw  = (const float*)d_in[3];  // [D, K]
    const int*   counter = (const int*)d_in[4];

    float* out = (float*)d_out;
    float* ste = out;                        // N*D
    float* out_perp = out + (size_t)N * D;   // 1
    float* out_loss = out_perp + 1;          // 1
    float* out_cb = out_perp + 2;            // D*K

    char* ws = (char*)d_ws;
    int* indices  = (int*)(ws + OFF_INDICES);
    int* perm     = (int*)(ws + OFF_PERM);
    int* counts   = (int*)(ws + OFF_COUNTS);
    int* offsets  = (int*)(ws + OFF_OFFSETS);
    int* cursor   = (int*)(ws + OFF_CURSOR);
    float* smooth = (float*)(ws + OFF_SMOOTH);
    float* lossp  = (float*)(ws + OFF_LOSSP);
    float* cnorm  = (float*)(ws + OFF_CNORM);
    float* cbT    = (float*)(ws + OFF_CBT);

    // zero the counts histogram only
    hipMemsetAsync(counts, 0, K * sizeof(int), stream);

    transpose_cb<<<dim3(32, 8), 256, 0, stream>>>(cb, cbT);
    cnorm_kernel<<<K / 256, 256, 0, stream>>>(cb, cnorm);
    argmin_kernel<<<N / 64, 256, 0, stream>>>(x, cb, cnorm, indices);
    quantize_kernel<<<QBLOCKS, 256, 0, stream>>>(x, cbT, indices, ste, counts, lossp);
    finalize_kernel<<<1, 1024, 0, stream>>>(counts, ema_c, counter, lossp,
                                            out_perp, out_loss, offsets, cursor, smooth);
    scatter_kernel<<<N / 256, 256, 0, stream>>>(indices, cursor, perm);
    dw_codebook_kernel<<<K, 256, 0, stream>>>(x, perm, offsets, counts, ema_dw,
                                              smooth, counter, out_cb);
}

// Round 3
// 783.828 us; speedup vs baseline: 2.3497x; 1.2944x over previous
//
#include <hip/hip_runtime.h>

// Problem constants
#define N 65536     // B*H*W rows
#define D 256
#define K 1024
#define BETA 0.25f
#define GAMMA 0.9f
#define EPS 1e-5f

#define QBLOCKS 512  // quantize kernel grid size (loss partials)

// Workspace layout (bytes)
#define OFF_INDICES 0                 // N int
#define OFF_PERM    262144            // N int
#define OFF_COUNTS  524288            // K int
#define OFF_OFFSETS 528384            // K int
#define OFF_CURSOR  532480            // K int
#define OFF_SMOOTH  536576            // K float
#define OFF_LOSSP   540672            // QBLOCKS floats (2 KB)
#define OFF_CNORM   542720            // K float
#define OFF_CBT     546816            // K*D float (1 MB)
#define OFF_CBT_HI  1595392           // K*D ushort (512 KB)
#define OFF_CBT_LO  2119680           // K*D ushort (512 KB); end 2643968

typedef __bf16 bf16x8 __attribute__((ext_vector_type(8)));
typedef short  s16x8  __attribute__((ext_vector_type(8)));
typedef float  f32x4  __attribute__((ext_vector_type(4)));

__device__ inline unsigned short f32_to_bf16_rn(float f) {
    unsigned int u = __float_as_uint(f);
    unsigned int r = u + 0x7fffu + ((u >> 16) & 1u);
    return (unsigned short)(r >> 16);
}

__device__ inline f32x4 mfma16(s16x8 a, s16x8 b, f32x4 c) {
    return __builtin_amdgcn_mfma_f32_16x16x32_bf16(
        __builtin_bit_cast(bf16x8, a), __builtin_bit_cast(bf16x8, b), c, 0, 0, 0);
}

// ---------------------------------------------------------------------------
// Transpose codebook [D][K] -> cbT [K][D] fp32 (for quantize: ste must be the
// EXACT fp32 codebook entries) + bf16 hi/lo splits (for MFMA argmin).
__global__ __launch_bounds__(256) void transpose_cb(const float* __restrict__ cb,
                                                    float* __restrict__ cbT,
                                                    unsigned short* __restrict__ cbT_hi,
                                                    unsigned short* __restrict__ cbT_lo) {
    __shared__ float tile[32][33];
    const int tx = threadIdx.x & 31;
    const int ty = threadIdx.x >> 5;       // 0..7
    const int k0 = blockIdx.x * 32;        // 32 blocks over K
    const int d0 = blockIdx.y * 32;        // 8 blocks over D
#pragma unroll
    for (int i = 0; i < 4; ++i)
        tile[ty + 8 * i][tx] = cb[(d0 + ty + 8 * i) * K + k0 + tx];
    __syncthreads();
#pragma unroll
    for (int i = 0; i < 4; ++i) {
        float v = tile[tx][ty + 8 * i];
        int idx = (k0 + ty + 8 * i) * D + d0 + tx;
        cbT[idx] = v;
        unsigned short h = f32_to_bf16_rn(v);
        cbT_hi[idx] = h;
        cbT_lo[idx] = f32_to_bf16_rn(v - __uint_as_float((unsigned)h << 16));
    }
}

// cnorm[k] = sum_d cb[d][k]^2  (fp32, matches reference precision)
__global__ __launch_bounds__(256) void cnorm_kernel(const float* __restrict__ cb,
                                                    float* __restrict__ cnorm) {
    const int k = blockIdx.x * 256 + threadIdx.x;
    float acc = 0.f;
    for (int d = 0; d < D; ++d) {
        float v = cb[d * K + k];
        acc = fmaf(v, v, acc);
    }
    cnorm[k] = acc;
}

// ---------------------------------------------------------------------------
// MFMA argmin. Block = 128 threads (2 waves), 32 rows. A tile (32x256) staged
// ONCE to LDS as bf16 hi/lo in MFMA A-operand order (lane-contiguous 16 B ->
// conflict-free ds_read_b128). Main loop: 8 col-tiles x 8 K-steps, 24 MFMAs
// (hi*hi + lo*hi + hi*lo) per wave-step; B frags direct from L1/L2-resident
// cbT_hi/lo (no staging, NO barriers in the hot loop).
// Layouts (measured, guide S3): A lane L holds A[m=L&15][k=(L>>4)*8+j];
// B lane L holds B[k=(L>>4)*8+j][n=L&15]; D: col=L&15, row=(L>>4)*4+reg.
__global__ __launch_bounds__(128) void argmin_mfma_kernel(
        const float* __restrict__ x,
        const unsigned short* __restrict__ cbT_hi,
        const unsigned short* __restrict__ cbT_lo,
        const float* __restrict__ cnorm,
        int* __restrict__ indices) {
    __shared__ unsigned short Ah[32 * 256];   // 16 KB, operand-order 16B units
    __shared__ unsigned short Al[32 * 256];   // 16 KB
    __shared__ float redv[2][32];
    __shared__ int   redi[2][32];

    const int tid = threadIdx.x;
    const int lane = tid & 63;
    const int wc = tid >> 6;        // wave col half: 0/1
    const int r0 = blockIdx.x * 32;
    const int row16 = lane & 15;
    const int quad = lane >> 4;

    // ---- stage A hi/lo into operand order ----
#pragma unroll
    for (int i = 0; i < 8; ++i) {
        int g = tid + 128 * i;          // 0..1023
        int r = g >> 5;                 // 0..31
        int kg = g & 31;                // k-group of 8
        const float* src = &x[(size_t)(r0 + r) * D + kg * 8];
        float4 v0 = *(const float4*)src;
        float4 v1 = *(const float4*)(src + 4);
        float xs[8] = {v0.x, v0.y, v0.z, v0.w, v1.x, v1.y, v1.z, v1.w};
        s16x8 hv, lv;
#pragma unroll
        for (int j = 0; j < 8; ++j) {
            unsigned short h = f32_to_bf16_rn(xs[j]);
            float hf = __uint_as_float((unsigned)h << 16);
            hv[j] = (short)h;
            lv[j] = (short)f32_to_bf16_rn(xs[j] - hf);
        }
        int unit = ((kg >> 2) * 2 + (r >> 4)) * 64 + ((kg & 3) * 16 + (r & 15));
        *(s16x8*)&Ah[unit * 8] = hv;
        *(s16x8*)&Al[unit * 8] = lv;
    }
    __syncthreads();

    float minv[2][4];
    int   mini[2][4];
#pragma unroll
    for (int fr = 0; fr < 2; ++fr)
#pragma unroll
        for (int reg = 0; reg < 4; ++reg) { minv[fr][reg] = 3.4e38f; mini[fr][reg] = 0; }

    for (int c = 0; c < 8; ++c) {
        const int cbase = c * 128 + wc * 64;
        f32x4 acc[2][4];
#pragma unroll
        for (int fr = 0; fr < 2; ++fr)
#pragma unroll
            for (int fc = 0; fc < 4; ++fc) acc[fr][fc] = (f32x4){0.f, 0.f, 0.f, 0.f};

#pragma unroll
        for (int ks = 0; ks < 8; ++ks) {
            s16x8 ah[2], al[2], bh[4], bl[4];
#pragma unroll
            for (int fr = 0; fr < 2; ++fr) {
                int unit = (ks * 2 + fr) * 64 + lane;
                ah[fr] = *(const s16x8*)&Ah[unit * 8];
                al[fr] = *(const s16x8*)&Al[unit * 8];
            }
#pragma unroll
            for (int fc = 0; fc < 4; ++fc) {
                size_t off = (size_t)(cbase + 16 * fc + row16) * D + ks * 32 + quad * 8;
                bh[fc] = *(const s16x8*)&cbT_hi[off];
                bl[fc] = *(const s16x8*)&cbT_lo[off];
            }
#pragma unroll
            for (int fc = 0; fc < 4; ++fc)
#pragma unroll
                for (int fr = 0; fr < 2; ++fr) {
                    acc[fr][fc] = mfma16(ah[fr], bh[fc], acc[fr][fc]);
                    acc[fr][fc] = mfma16(al[fr], bh[fc], acc[fr][fc]);
                    acc[fr][fc] = mfma16(ah[fr], bl[fc], acc[fr][fc]);
                }
        }
        // argmin epilogue for this col tile (fc ascending => strict < keeps lowest col)
#pragma unroll
        for (int fc = 0; fc < 4; ++fc) {
            int col = cbase + 16 * fc + row16;
            float cn = cnorm[col];
#pragma unroll
            for (int fr = 0; fr < 2; ++fr)
#pragma unroll
                for (int reg = 0; reg < 4; ++reg) {
                    float val = fmaf(-2.f, acc[fr][fc][reg], cn);
                    if (val < minv[fr][reg]) { minv[fr][reg] = val; mini[fr][reg] = col; }
                }
        }
    }

    // butterfly over the 16-lane col group (rows identical across lane&15)
#pragma unroll
    for (int mask = 1; mask <= 8; mask <<= 1) {
#pragma unroll
        for (int fr = 0; fr < 2; ++fr)
#pragma unroll
            for (int reg = 0; reg < 4; ++reg) {
                float ov = __shfl_xor(minv[fr][reg], mask, 64);
                int   oi = __shfl_xor(mini[fr][reg], mask, 64);
                if (ov < minv[fr][reg] ||
                    (ov == minv[fr][reg] && oi < mini[fr][reg])) {
                    minv[fr][reg] = ov; mini[fr][reg] = oi;
                }
            }
    }
    if (row16 == 0) {
#pragma unroll
        for (int fr = 0; fr < 2; ++fr)
#pragma unroll
            for (int reg = 0; reg < 4; ++reg) {
                int row = 16 * fr + 4 * quad + reg;
                redv[wc][row] = minv[fr][reg];
                redi[wc][row] = mini[fr][reg];
            }
    }
    __syncthreads();
    if (tid < 32) {
        float v0 = redv[0][tid]; int i0 = redi[0][tid];
        float v1 = redv[1][tid]; int i1 = redi[1][tid];
        indices[r0 + tid] = (v1 < v0 || (v1 == v0 && i1 < i0)) ? i1 : i0;
    }
}

// ---------------------------------------------------------------------------
// ste (= quantized, exact fp32 codebook rows) + loss partials + histogram.
__global__ __launch_bounds__(256) void quantize_kernel(const float* __restrict__ x,
                                                       const float* __restrict__ cbT,
                                                       const int* __restrict__ indices,
                                                       float* __restrict__ ste,
                                                       int* __restrict__ counts,
                                                       float* __restrict__ loss_partial) {
    const int lane = threadIdx.x & 63;
    const int wid = (blockIdx.x * 256 + threadIdx.x) >> 6;   // global wave id
    const int nwaves = QBLOCKS * 4;

    float s = 0.f;
    for (int row = wid; row < N; row += nwaves) {
        const int k = indices[row];
        float4 q  = *(const float4*)&cbT[k * D + lane * 4];   // L2-resident (1 MB)
        float4 xi = *(const float4*)&x[(size_t)row * D + lane * 4];
        *(float4*)&ste[(size_t)row * D + lane * 4] = q;
        float dx = q.x - xi.x, dy = q.y - xi.y, dz = q.z - xi.z, dw = q.w - xi.w;
        s = fmaf(dx, dx, s); s = fmaf(dy, dy, s);
        s = fmaf(dz, dz, s); s = fmaf(dw, dw, s);
        if (lane == 0) atomicAdd(&counts[k], 1);    // 1024-way spread
    }
#pragma unroll
    for (int off = 32; off >= 1; off >>= 1) s += __shfl_down(s, off, 64);
    __shared__ float red[4];
    if (lane == 0) red[threadIdx.x >> 6] = s;
    __syncthreads();
    if (threadIdx.x == 0)
        loss_partial[blockIdx.x] = red[0] + red[1] + red[2] + red[3];
}

// ---------------------------------------------------------------------------
// Single block: EMA cluster stats, perplexity, loss finalize, prefix-sum, cursor
__global__ __launch_bounds__(1024) void finalize_kernel(const int* __restrict__ counts,
                                                        const float* __restrict__ ema_c,
                                                        const int* __restrict__ counter,
                                                        const float* __restrict__ loss_partial,
                                                        float* __restrict__ out_perp,
                                                        float* __restrict__ out_loss,
                                                        int* __restrict__ offsets,
                                                        int* __restrict__ cursor,
                                                        float* __restrict__ smoothed) {
    const int k = threadIdx.x;
    __shared__ float fred[1024];
    __shared__ int scan[1024];
    __shared__ float nsum_s;
    __shared__ float ent_s;

    const int c = counts[k];
    const float bias = 1.0f - powf(GAMMA, (float)counter[0]);
    const float hid = fmaf(ema_c[k], GAMMA, (float)c * (1.0f - GAMMA));
    const float avg = hid / bias;

    fred[k] = avg;
    __syncthreads();
    for (int s = 512; s >= 1; s >>= 1) {
        if (k < s) fred[k] += fred[k + s];
        __syncthreads();
    }
    if (k == 0) nsum_s = fred[0];
    __syncthreads();
    const float nsum = nsum_s;

    float p = (float)c * (1.0f / (float)N);
    fred[k] = p * logf(p + 1e-10f);
    __syncthreads();
    for (int s = 512; s >= 1; s >>= 1) {
        if (k < s) fred[k] += fred[k + s];
        __syncthreads();
    }
    if (k == 0) ent_s = fred[0];
    __syncthreads();

    fred[k] = (k < QBLOCKS) ? loss_partial[k] : 0.f;
    __syncthreads();
    for (int s = 512; s >= 1; s >>= 1) {
        if (k < s) fred[k] += fred[k + s];
        __syncthreads();
    }

    scan[k] = c;
    __syncthreads();
    for (int s = 1; s < 1024; s <<= 1) {
        int v = (k >= s) ? scan[k - s] : 0;
        __syncthreads();
        scan[k] += v;
        __syncthreads();
    }
    const int excl = scan[k] - c;
    offsets[k] = excl;
    cursor[k] = excl;

    smoothed[k] = (avg + EPS) / (nsum + (float)K * EPS) * nsum;

    if (k == 0) {
        out_perp[0] = expf(-ent_s);
        out_loss[0] = BETA * fred[0] * (1.0f / ((float)N * (float)D));
    }
}

// Build permutation: rows grouped by cluster
__global__ __launch_bounds__(256) void scatter_kernel(const int* __restrict__ indices,
                                                      int* __restrict__ cursor,
                                                      int* __restrict__ perm) {
    const int n = blockIdx.x * 256 + threadIdx.x;
    const int k = indices[n];
    const int pos = atomicAdd(&cursor[k], 1);
    perm[pos] = n;
}

// ---------------------------------------------------------------------------
// dw[:,k] = sum of member rows; new_codebook = ((ema_dw*g + dw*(1-g))/bias)/smoothed
__global__ __launch_bounds__(256) void dw_codebook_kernel(const float* __restrict__ x,
                                                          const int* __restrict__ perm,
                                                          const int* __restrict__ offsets,
                                                          const int* __restrict__ counts,
                                                          const float* __restrict__ ema_dw,
                                                          const float* __restrict__ smoothed,
                                                          const int* __restrict__ counter,
                                                          float* __restrict__ out_cb) {
    const int k = blockIdx.x;
    const int d = threadIdx.x;
    const int off = offsets[k];
    const int cnt = counts[k];
    float acc = 0.f;
    int i = 0;
    for (; i + 4 <= cnt; i += 4) {
        int n0 = perm[off + i + 0];
        int n1 = perm[off + i + 1];
        int n2 = perm[off + i + 2];
        int n3 = perm[off + i + 3];
        acc += x[n0 * D + d] + x[n1 * D + d] + x[n2 * D + d] + x[n3 * D + d];
    }
    for (; i < cnt; ++i) acc += x[perm[off + i] * D + d];
    const float bias = 1.0f - powf(GAMMA, (float)counter[0]);
    const float hid = fmaf(ema_dw[d * K + k], GAMMA, acc * (1.0f - GAMMA));
    out_cb[d * K + k] = (hid / bias) / smoothed[k];
}

// ---------------------------------------------------------------------------
extern "C" void kernel_launch(void* const* d_in, const int* in_sizes, int n_in,
                              void* d_out, int out_size, void* d_ws, size_t ws_size,
                              hipStream_t stream) {
    const float* x       = (const float*)d_in[0];  // [N, D]
    const float* cb      = (const float*)d_in[1];  // [D, K]
    const float* ema_c   = (const float*)d_in[2];  // [K]
    const float* ema_dw  = (const float*)d_in[3];  // [D, K]
    const int*   counter = (const int*)d_in[4];

    float* out = (float*)d_out;
    float* ste = out;                        // N*D
    float* out_perp = out + (size_t)N * D;   // 1
    float* out_loss = out_perp + 1;          // 1
    float* out_cb = out_perp + 2;            // D*K

    char* ws = (char*)d_ws;
    int* indices  = (int*)(ws + OFF_INDICES);
    int* perm     = (int*)(ws + OFF_PERM);
    int* counts   = (int*)(ws + OFF_COUNTS);
    int* offsets  = (int*)(ws + OFF_OFFSETS);
    int* cursor   = (int*)(ws + OFF_CURSOR);
    float* smooth = (float*)(ws + OFF_SMOOTH);
    float* lossp  = (float*)(ws + OFF_LOSSP);
    float* cnorm  = (float*)(ws + OFF_CNORM);
    float* cbT    = (float*)(ws + OFF_CBT);
    unsigned short* cbT_hi = (unsigned short*)(ws + OFF_CBT_HI);
    unsigned short* cbT_lo = (unsigned short*)(ws + OFF_CBT_LO);

    hipMemsetAsync(counts, 0, K * sizeof(int), stream);

    transpose_cb<<<dim3(32, 8), 256, 0, stream>>>(cb, cbT, cbT_hi, cbT_lo);
    cnorm_kernel<<<K / 256, 256, 0, stream>>>(cb, cnorm);
    argmin_mfma_kernel<<<N / 32, 128, 0, stream>>>(x, cbT_hi, cbT_lo, cnorm, indices);
    quantize_kernel<<<QBLOCKS, 256, 0, stream>>>(x, cbT, indices, ste, counts, lossp);
    finalize_kernel<<<1, 1024, 0, stream>>>(counts, ema_c, counter, lossp,
                                            out_perp, out_loss, offsets, cursor, smooth);
    scatter_kernel<<<N / 256, 256, 0, stream>>>(indices, cursor, perm);
    dw_codebook_kernel<<<K, 256, 0, stream>>>(x, perm, offsets, counts, ema_dw,
                                              smooth, counter, out_cb);
}

// Round 4
// 757.502 us; speedup vs baseline: 2.4314x; 1.0348x over previous
//
#include <hip/hip_runtime.h>

// Problem constants
#define N 65536     // B*H*W rows
#define D 256
#define K 1024
#define BETA 0.25f
#define GAMMA 0.9f
#define EPS 1e-5f

#define QBLOCKS 512  // quantize kernel grid size (loss partials)

// Workspace layout (bytes)
#define OFF_INDICES 0                 // N int
#define OFF_PERM    262144            // N int
#define OFF_COUNTS  524288            // K int
#define OFF_OFFSETS 528384            // K int
#define OFF_CURSOR  532480            // K int
#define OFF_SMOOTH  536576            // K float
#define OFF_LOSSP   540672            // QBLOCKS floats (2 KB)
#define OFF_CNORM   542720            // K float
#define OFF_CBT     546816            // K*D float (1 MB)
#define OFF_CBE     1595392           // K*768 ushort (1.5 MB); end 3168256

typedef __bf16 bf16x8 __attribute__((ext_vector_type(8)));
typedef short  s16x8  __attribute__((ext_vector_type(8)));
typedef float  f32x4  __attribute__((ext_vector_type(4)));

__device__ inline unsigned short f32_to_bf16_rn(float f) {
    unsigned int u = __float_as_uint(f);
    unsigned int r = u + 0x7fffu + ((u >> 16) & 1u);
    return (unsigned short)(r >> 16);
}

__device__ inline f32x4 mfma16(s16x8 a, s16x8 b, f32x4 c) {
    return __builtin_amdgcn_mfma_f32_16x16x32_bf16(
        __builtin_bit_cast(bf16x8, a), __builtin_bit_cast(bf16x8, b), c, 0, 0, 0);
}

// ---------------------------------------------------------------------------
// Transpose codebook [D][K] -> cbT [K][D] fp32 (quantize needs exact entries)
// + cbE [K][768] bf16 folded-K table: [e_hi | e_hi | e_lo].
__global__ __launch_bounds__(256) void transpose_cb(const float* __restrict__ cb,
                                                    float* __restrict__ cbT,
                                                    unsigned short* __restrict__ cbE) {
    __shared__ float tile[32][33];
    const int tx = threadIdx.x & 31;
    const int ty = threadIdx.x >> 5;       // 0..7
    const int k0 = blockIdx.x * 32;        // 32 blocks over K
    const int d0 = blockIdx.y * 32;        // 8 blocks over D
#pragma unroll
    for (int i = 0; i < 4; ++i)
        tile[ty + 8 * i][tx] = cb[(d0 + ty + 8 * i) * K + k0 + tx];
    __syncthreads();
#pragma unroll
    for (int i = 0; i < 4; ++i) {
        float v = tile[tx][ty + 8 * i];
        int c = k0 + ty + 8 * i;
        int d = d0 + tx;
        cbT[c * D + d] = v;
        unsigned short h = f32_to_bf16_rn(v);
        unsigned short l = f32_to_bf16_rn(v - __uint_as_float((unsigned)h << 16));
        cbE[c * 768 + d]       = h;
        cbE[c * 768 + 256 + d] = h;
        cbE[c * 768 + 512 + d] = l;
    }
}

// cnorm[k] = sum_d cb[d][k]^2  (fp32, matches reference precision)
__global__ __launch_bounds__(256) void cnorm_kernel(const float* __restrict__ cb,
                                                    float* __restrict__ cnorm) {
    const int k = blockIdx.x * 256 + threadIdx.x;
    float acc = 0.f;
    for (int d = 0; d < D; ++d) {
        float v = cb[d * K + k];
        acc = fmaf(v, v, acc);
    }
    cnorm[k] = acc;
}

// ---------------------------------------------------------------------------
// Folded-K MFMA argmin GEMM. M-tile=64 rows/block, col loop 8 x 128 cols,
// Keff=768, BK=64. 256 threads = 4 waves in 2x2 (wr=row half of 32, wc=col
// half of 64). Per kb iter: stage A (fp32->bf16 convert, swizzled operand
// order, <=2-way write banks) + stage B (cbE copy, XOR-swizzled slots) ->
// barrier -> 2 ks x (2 A-frags + 4 B-frags ds_read_b128 + 8 MFMAs).
// Fragment conventions verified in R3: A lane L = A[m=L&15][k-octet L>>4];
// B (from [col][k] array) lane L = col L&15, k-octet L>>4; D: col=L&15,
// row=quad*4+reg.
__global__ __launch_bounds__(256, 3) void argmin_mfma_kernel(
        const float* __restrict__ x,
        const unsigned short* __restrict__ cbE,
        const float* __restrict__ cnorm,
        int* __restrict__ indices) {
    __shared__ unsigned short As[8 * 512];    // 8 units x 64 slots x 8 ushorts = 8 KB
    __shared__ unsigned short Bs[1024 * 8];   // 1024 slots x 16 B = 16 KB
    __shared__ float redv[2][64];
    __shared__ int   redi[2][64];

    const int tid = threadIdx.x;
    const int lane = tid & 63;
    const int wave = tid >> 6;
    const int wr = wave >> 1;      // row half (32 rows)
    const int wc = wave & 1;       // col half (64 cols)
    const int r0 = blockIdx.x * 64;
    const int colLane = lane & 15;
    const int quad = lane >> 4;

    // A read-slot swizzle (matches staging write swizzle), per ks
    const int aslot0 = quad * 16 + ((colLane + 4 * quad) & 15);
    const int aslot1 = quad * 16 + ((colLane + 4 * quad + 2) & 15);

    float minv[2][4];
    int   mini[2][4];
#pragma unroll
    for (int fr = 0; fr < 2; ++fr)
#pragma unroll
        for (int reg = 0; reg < 4; ++reg) { minv[fr][reg] = 3.4e38f; mini[fr][reg] = 0; }

    for (int ct = 0; ct < 8; ++ct) {
        f32x4 acc[2][4];
#pragma unroll
        for (int fr = 0; fr < 2; ++fr)
#pragma unroll
            for (int fc = 0; fc < 4; ++fc) acc[fr][fc] = (f32x4){0.f, 0.f, 0.f, 0.f};

        for (int kb = 0; kb < 12; ++kb) {
            __syncthreads();   // prior iter's frag reads done before restage
            // ---- stage A: 64 rows x 64 k, fp32 -> bf16 (hi or lo by part) ----
            const int part = kb >> 2;            // 0:hi 1:lo 2:hi
            const int doff = (kb & 3) * 64;
#pragma unroll
            for (int p = 0; p < 2; ++p) {
                int id = p * 256 + tid;          // 0..511
                int r = id >> 3;                 // 0..63
                int kc = id & 7;                 // 8-k chunk
                const float* src = &x[(size_t)(r0 + r) * D + doff + kc * 8];
                float4 v0 = *(const float4*)src;
                float4 v1 = *(const float4*)(src + 4);
                float f[8] = {v0.x, v0.y, v0.z, v0.w, v1.x, v1.y, v1.z, v1.w};
                s16x8 outv;
#pragma unroll
                for (int j = 0; j < 8; ++j) {
                    unsigned short h = f32_to_bf16_rn(f[j]);
                    if (part == 1)
                        h = f32_to_bf16_rn(f[j] - __uint_as_float((unsigned)h << 16));
                    outv[j] = (short)h;
                }
                int m = r & 15, rg = r >> 4, ks = kc >> 2, o = kc & 3;
                int slot = o * 16 + ((m + 4 * o + 2 * ks) & 15);
                *(s16x8*)&As[(ks * 4 + rg) * 512 + slot * 8] = outv;
            }
            // ---- stage B: 128 cols x 64 k from cbE, XOR-swizzled slots ----
#pragma unroll
            for (int i = 0; i < 4; ++i) {
                int id = i * 256 + tid;          // 0..1023 slot
                int col = id >> 3;
                int kc = (id & 7) ^ (col & 7);
                s16x8 v = *(const s16x8*)&cbE[(size_t)(ct * 128 + col) * 768 + kb * 64 + kc * 8];
                *(s16x8*)&Bs[id * 8] = v;
            }
            __syncthreads();
            // ---- compute: 2 ks x 8 MFMAs ----
#pragma unroll
            for (int ks = 0; ks < 2; ++ks) {
                s16x8 a[2], b[4];
                const int aslot = ks ? aslot1 : aslot0;
#pragma unroll
                for (int fr = 0; fr < 2; ++fr)
                    a[fr] = *(const s16x8*)&As[(ks * 4 + wr * 2 + fr) * 512 + aslot * 8];
#pragma unroll
                for (int fc = 0; fc < 4; ++fc) {
                    int cl = wc * 64 + fc * 16 + colLane;
                    int slot = cl * 8 + ((ks * 4 + quad) ^ (cl & 7));
                    b[fc] = *(const s16x8*)&Bs[slot * 8];
                }
#pragma unroll
                for (int fc = 0; fc < 4; ++fc)
#pragma unroll
                    for (int fr = 0; fr < 2; ++fr)
                        acc[fr][fc] = mfma16(a[fr], b[fc], acc[fr][fc]);
            }
        }
        // ---- argmin epilogue for this col tile (ascending col, strict <) ----
#pragma unroll
        for (int fc = 0; fc < 4; ++fc) {
            int col = ct * 128 + wc * 64 + fc * 16 + colLane;
            float cn = cnorm[col];
#pragma unroll
            for (int fr = 0; fr < 2; ++fr)
#pragma unroll
                for (int reg = 0; reg < 4; ++reg) {
                    float val = fmaf(-2.f, acc[fr][fc][reg], cn);
                    if (val < minv[fr][reg]) { minv[fr][reg] = val; mini[fr][reg] = col; }
                }
        }
    }

    // butterfly over the 16-lane col group; tie -> lower index
#pragma unroll
    for (int mask = 1; mask <= 8; mask <<= 1) {
#pragma unroll
        for (int fr = 0; fr < 2; ++fr)
#pragma unroll
            for (int reg = 0; reg < 4; ++reg) {
                float ov = __shfl_xor(minv[fr][reg], mask, 64);
                int   oi = __shfl_xor(mini[fr][reg], mask, 64);
                if (ov < minv[fr][reg] ||
                    (ov == minv[fr][reg] && oi < mini[fr][reg])) {
                    minv[fr][reg] = ov; mini[fr][reg] = oi;
                }
            }
    }
    if (colLane == 0) {
#pragma unroll
        for (int fr = 0; fr < 2; ++fr)
#pragma unroll
            for (int reg = 0; reg < 4; ++reg) {
                int row = wr * 32 + fr * 16 + quad * 4 + reg;
                redv[wc][row] = minv[fr][reg];
                redi[wc][row] = mini[fr][reg];
            }
    }
    __syncthreads();
    if (tid < 64) {
        float v0 = redv[0][tid]; int i0 = redi[0][tid];
        float v1 = redv[1][tid]; int i1 = redi[1][tid];
        indices[r0 + tid] = (v1 < v0 || (v1 == v0 && i1 < i0)) ? i1 : i0;
    }
}

// ---------------------------------------------------------------------------
// ste (= quantized, exact fp32 codebook rows) + loss partials + histogram.
__global__ __launch_bounds__(256) void quantize_kernel(const float* __restrict__ x,
                                                       const float* __restrict__ cbT,
                                                       const int* __restrict__ indices,
                                                       float* __restrict__ ste,
                                                       int* __restrict__ counts,
                                                       float* __restrict__ loss_partial) {
    const int lane = threadIdx.x & 63;
    const int wid = (blockIdx.x * 256 + threadIdx.x) >> 6;   // global wave id
    const int nwaves = QBLOCKS * 4;

    float s = 0.f;
    for (int row = wid; row < N; row += nwaves) {
        const int k = indices[row];
        float4 q  = *(const float4*)&cbT[k * D + lane * 4];   // L2-resident (1 MB)
        float4 xi = *(const float4*)&x[(size_t)row * D + lane * 4];
        *(float4*)&ste[(size_t)row * D + lane * 4] = q;
        float dx = q.x - xi.x, dy = q.y - xi.y, dz = q.z - xi.z, dw = q.w - xi.w;
        s = fmaf(dx, dx, s); s = fmaf(dy, dy, s);
        s = fmaf(dz, dz, s); s = fmaf(dw, dw, s);
        if (lane == 0) atomicAdd(&counts[k], 1);    // 1024-way spread
    }
#pragma unroll
    for (int off = 32; off >= 1; off >>= 1) s += __shfl_down(s, off, 64);
    __shared__ float red[4];
    if (lane == 0) red[threadIdx.x >> 6] = s;
    __syncthreads();
    if (threadIdx.x == 0)
        loss_partial[blockIdx.x] = red[0] + red[1] + red[2] + red[3];
}

// ---------------------------------------------------------------------------
// Single block: EMA cluster stats, perplexity, loss finalize, prefix-sum, cursor
__global__ __launch_bounds__(1024) void finalize_kernel(const int* __restrict__ counts,
                                                        const float* __restrict__ ema_c,
                                                        const int* __restrict__ counter,
                                                        const float* __restrict__ loss_partial,
                                                        float* __restrict__ out_perp,
                                                        float* __restrict__ out_loss,
                                                        int* __restrict__ offsets,
                                                        int* __restrict__ cursor,
                                                        float* __restrict__ smoothed) {
    const int k = threadIdx.x;
    __shared__ float fred[1024];
    __shared__ int scan[1024];
    __shared__ float nsum_s;
    __shared__ float ent_s;

    const int c = counts[k];
    const float bias = 1.0f - powf(GAMMA, (float)counter[0]);
    const float hid = fmaf(ema_c[k], GAMMA, (float)c * (1.0f - GAMMA));
    const float avg = hid / bias;

    fred[k] = avg;
    __syncthreads();
    for (int s = 512; s >= 1; s >>= 1) {
        if (k < s) fred[k] += fred[k + s];
        __syncthreads();
    }
    if (k == 0) nsum_s = fred[0];
    __syncthreads();
    const float nsum = nsum_s;

    float p = (float)c * (1.0f / (float)N);
    fred[k] = p * logf(p + 1e-10f);
    __syncthreads();
    for (int s = 512; s >= 1; s >>= 1) {
        if (k < s) fred[k] += fred[k + s];
        __syncthreads();
    }
    if (k == 0) ent_s = fred[0];
    __syncthreads();

    fred[k] = (k < QBLOCKS) ? loss_partial[k] : 0.f;
    __syncthreads();
    for (int s = 512; s >= 1; s >>= 1) {
        if (k < s) fred[k] += fred[k + s];
        __syncthreads();
    }

    scan[k] = c;
    __syncthreads();
    for (int s = 1; s < 1024; s <<= 1) {
        int v = (k >= s) ? scan[k - s] : 0;
        __syncthreads();
        scan[k] += v;
        __syncthreads();
    }
    const int excl = scan[k] - c;
    offsets[k] = excl;
    cursor[k] = excl;

    smoothed[k] = (avg + EPS) / (nsum + (float)K * EPS) * nsum;

    if (k == 0) {
        out_perp[0] = expf(-ent_s);
        out_loss[0] = BETA * fred[0] * (1.0f / ((float)N * (float)D));
    }
}

// Build permutation: rows grouped by cluster
__global__ __launch_bounds__(256) void scatter_kernel(const int* __restrict__ indices,
                                                      int* __restrict__ cursor,
                                                      int* __restrict__ perm) {
    const int n = blockIdx.x * 256 + threadIdx.x;
    const int k = indices[n];
    const int pos = atomicAdd(&cursor[k], 1);
    perm[pos] = n;
}

// ---------------------------------------------------------------------------
// dw[:,k] = sum of member rows; new_codebook = ((ema_dw*g + dw*(1-g))/bias)/smoothed
__global__ __launch_bounds__(256) void dw_codebook_kernel(const float* __restrict__ x,
                                                          const int* __restrict__ perm,
                                                          const int* __restrict__ offsets,
                                                          const int* __restrict__ counts,
                                                          const float* __restrict__ ema_dw,
                                                          const float* __restrict__ smoothed,
                                                          const int* __restrict__ counter,
                                                          float* __restrict__ out_cb) {
    const int k = blockIdx.x;
    const int d = threadIdx.x;
    const int off = offsets[k];
    const int cnt = counts[k];
    float acc = 0.f;
    int i = 0;
    for (; i + 4 <= cnt; i += 4) {
        int n0 = perm[off + i + 0];
        int n1 = perm[off + i + 1];
        int n2 = perm[off + i + 2];
        int n3 = perm[off + i + 3];
        acc += x[n0 * D + d] + x[n1 * D + d] + x[n2 * D + d] + x[n3 * D + d];
    }
    for (; i < cnt; ++i) acc += x[perm[off + i] * D + d];
    const float bias = 1.0f - powf(GAMMA, (float)counter[0]);
    const float hid = fmaf(ema_dw[d * K + k], GAMMA, acc * (1.0f - GAMMA));
    out_cb[d * K + k] = (hid / bias) / smoothed[k];
}

// ---------------------------------------------------------------------------
extern "C" void kernel_launch(void* const* d_in, const int* in_sizes, int n_in,
                              void* d_out, int out_size, void* d_ws, size_t ws_size,
                              hipStream_t stream) {
    const float* x       = (const float*)d_in[0];  // [N, D]
    const float* cb      = (const float*)d_in[1];  // [D, K]
    const float* ema_c   = (const float*)d_in[2];  // [K]
    const float* ema_dw  = (const float*)d_in[3];  // [D, K]
    const int*   counter = (const int*)d_in[4];

    float* out = (float*)d_out;
    float* ste = out;                        // N*D
    float* out_perp = out + (size_t)N * D;   // 1
    float* out_loss = out_perp + 1;          // 1
    float* out_cb = out_perp + 2;            // D*K

    char* ws = (char*)d_ws;
    int* indices  = (int*)(ws + OFF_INDICES);
    int* perm     = (int*)(ws + OFF_PERM);
    int* counts   = (int*)(ws + OFF_COUNTS);
    int* offsets  = (int*)(ws + OFF_OFFSETS);
    int* cursor   = (int*)(ws + OFF_CURSOR);
    float* smooth = (float*)(ws + OFF_SMOOTH);
    float* lossp  = (float*)(ws + OFF_LOSSP);
    float* cnorm  = (float*)(ws + OFF_CNORM);
    float* cbT    = (float*)(ws + OFF_CBT);
    unsigned short* cbE = (unsigned short*)(ws + OFF_CBE);

    hipMemsetAsync(counts, 0, K * sizeof(int), stream);

    transpose_cb<<<dim3(32, 8), 256, 0, stream>>>(cb, cbT, cbE);
    cnorm_kernel<<<K / 256, 256, 0, stream>>>(cb, cnorm);
    argmin_mfma_kernel<<<N / 64, 256, 0, stream>>>(x, cbE, cnorm, indices);
    quantize_kernel<<<QBLOCKS, 256, 0, stream>>>(x, cbT, indices, ste, counts, lossp);
    finalize_kernel<<<1, 1024, 0, stream>>>(counts, ema_c, counter, lossp,
                                            out_perp, out_loss, offsets, cursor, smooth);
    scatter_kernel<<<N / 256, 256, 0, stream>>>(indices, cursor, perm);
    dw_codebook_kernel<<<K, 256, 0, stream>>>(x, perm, offsets, counts, ema_dw,
                                              smooth, counter, out_cb);
}

// Round 5
// 565.280 us; speedup vs baseline: 3.2581x; 1.3400x over previous
//
#include <hip/hip_runtime.h>

// Problem constants
#define N 65536     // B*H*W rows
#define D 256
#define K 1024
#define BETA 0.25f
#define GAMMA 0.9f
#define EPS 1e-5f

#define QBLOCKS 512  // quantize kernel grid size (loss partials)

// Workspace layout (bytes)
#define OFF_INDICES 0                 // N int
#define OFF_PERM    262144            // N int
#define OFF_COUNTS  524288            // K int      -- memset with cnorm (8 KB)
#define OFF_CNORM   528384            // K float
#define OFF_OFFSETS 532480            // K int
#define OFF_CURSOR  536576            // K int
#define OFF_SMOOTH  540672            // K float
#define OFF_LOSSP   544768            // QBLOCKS floats (2 KB)
#define OFF_CBT     546816            // K*D float (1 MB)
#define OFF_CBE     1595392           // packed B: 16ct x 8kbp x 512units x 16B = 1 MB; end 2643968

// B physical chunk for logical kb (0..11): terms [xh*eh | xl*eh | xh*el]
// B needs hi for kb 0..7, lo for kb 8..11; hi chunks 0-3, lo chunks 4-7.
#define KBP(kb) (((kb) < 8) ? ((kb) & 3) : (4 + ((kb) & 3)))

typedef __bf16 bf16x8 __attribute__((ext_vector_type(8)));
typedef short  s16x8  __attribute__((ext_vector_type(8)));
typedef float  f32x4  __attribute__((ext_vector_type(4)));

__device__ inline unsigned short f32_to_bf16_rn(float f) {
    unsigned int u = __float_as_uint(f);
    unsigned int r = u + 0x7fffu + ((u >> 16) & 1u);
    return (unsigned short)(r >> 16);
}

__device__ inline f32x4 mfma16(s16x8 a, s16x8 b, f32x4 c) {
    return __builtin_amdgcn_mfma_f32_16x16x32_bf16(
        __builtin_bit_cast(bf16x8, a), __builtin_bit_cast(bf16x8, b), c, 0, 0, 0);
}

// ---------------------------------------------------------------------------
// pack_cb: cb [D][K] -> cbT [K][D] fp32 (quantize needs exact entries)
//        + cbEp packed bf16 B-fragment units + cnorm (atomic partials).
// Unit order for a 64col x 64k tile: u = (frgc*2+ks)*64 + (o&3)*16 + (c&15),
// frgc=c>>4, ks=o>>2 -> a fragment read is 64 consecutive 16-B units.
// grid 64 blocks = (16 col-tiles x 4 d-chunks), 256 threads, 2 units/thread.
__global__ __launch_bounds__(256) void pack_cb(const float* __restrict__ cb,
                                               float* __restrict__ cbT,
                                               s16x8* __restrict__ cbEp,
                                               float* __restrict__ cnorm) {
    const int ct = blockIdx.x >> 2;
    const int c2 = blockIdx.x & 3;
#pragma unroll
    for (int it = 0; it < 2; ++it) {
        int u = it * 256 + threadIdx.x;
        int frgc = u >> 7;
        int ks = (u >> 6) & 1;
        int L = u & 63;
        int c = ct * 64 + frgc * 16 + (L & 15);
        int d0 = c2 * 64 + (ks * 4 + (L >> 4)) * 8;
        float v[8];
        s16x8 hv, lv;
        float ss = 0.f;
#pragma unroll
        for (int j = 0; j < 8; ++j) {
            float f = cb[(size_t)(d0 + j) * K + c];
            v[j] = f;
            unsigned short h = f32_to_bf16_rn(f);
            hv[j] = (short)h;
            lv[j] = (short)f32_to_bf16_rn(f - __uint_as_float((unsigned)h << 16));
            ss = fmaf(f, f, ss);
        }
        *(float4*)&cbT[(size_t)c * D + d0]     = make_float4(v[0], v[1], v[2], v[3]);
        *(float4*)&cbT[(size_t)c * D + d0 + 4] = make_float4(v[4], v[5], v[6], v[7]);
        cbEp[(size_t)(ct * 8 + c2) * 512 + u]     = hv;   // hi chunk
        cbEp[(size_t)(ct * 8 + 4 + c2) * 512 + u] = lv;   // lo chunk
        atomicAdd(&cnorm[c], ss);                          // 32 adds/col total
    }
}

// ---------------------------------------------------------------------------
// Register-A MFMA argmin. grid 512 blocks x 256 thr (4 waves), 128 rows/block.
// Each wave owns 32 rows: converts x -> bf16 hi/lo A-fragments ONCE into
// 128 VGPRs (2 frg x 8 k-octets x hi/lo). Col loop: 16 tiles of 64 cols;
// per tile 12 logical kb (K=64 each): B tile (8 KB) software-pipelined
// through a double-buffered LDS: next tile's global loads issue BEFORE
// compute, ds_write after -> loads fly across the 16-MFMA compute phase.
// All LDS accesses are consecutive-16B-per-lane: conflict-free.
// Verified layouts (R3): A lane L = A[m=L&15][k=(L>>4)*8+j];
// B lane L = B[k=(L>>4)*8+j][n=L&15]; D: col=L&15, row=(L>>4)*4+reg.
__global__ __launch_bounds__(256, 2) void argmin_mfma_kernel(
        const float* __restrict__ x,
        const s16x8* __restrict__ cbEp,
        const float* __restrict__ cnorm,
        int* __restrict__ indices) {
    __shared__ s16x8 Bs[2][512];   // 16 KB double buffer

    const int tid = threadIdx.x;
    const int lane = tid & 63;
    const int w = tid >> 6;            // wave id 0..3 (32 rows each)
    const int r0 = blockIdx.x * 128;
    const int row16 = lane & 15;
    const int quad = lane >> 4;

    // ---- phase 1: load + convert this wave's 32 rows into A fragments ----
    s16x8 Ah[2][8], Al[2][8];
#pragma unroll
    for (int frg = 0; frg < 2; ++frg) {
#pragma unroll
        for (int kb8 = 0; kb8 < 8; ++kb8) {
            const float* src = &x[(size_t)(r0 + w * 32 + frg * 16 + row16) * D
                                  + kb8 * 32 + quad * 8];
            float4 v0 = *(const float4*)src;
            float4 v1 = *(const float4*)(src + 4);
            float f[8] = {v0.x, v0.y, v0.z, v0.w, v1.x, v1.y, v1.z, v1.w};
            s16x8 hv, lv;
#pragma unroll
            for (int j = 0; j < 8; ++j) {
                unsigned short h = f32_to_bf16_rn(f[j]);
                hv[j] = (short)h;
                lv[j] = (short)f32_to_bf16_rn(f[j] - __uint_as_float((unsigned)h << 16));
            }
            Ah[frg][kb8] = hv;
            Al[frg][kb8] = lv;
        }
    }

    float minv[2][4];
    int   mini[2][4];
#pragma unroll
    for (int frg = 0; frg < 2; ++frg)
#pragma unroll
        for (int reg = 0; reg < 4; ++reg) { minv[frg][reg] = 3.4e38f; mini[frg][reg] = 0; }

    // ---- prologue: stage B(ct=0, kb=0) into buf0 ----
    {
        s16x8 p0 = cbEp[tid];
        s16x8 p1 = cbEp[256 + tid];
        Bs[0][tid] = p0;
        Bs[0][256 + tid] = p1;
    }

    for (int ct = 0; ct < 16; ++ct) {
        f32x4 acc[2][4];
#pragma unroll
        for (int frg = 0; frg < 2; ++frg)
#pragma unroll
            for (int fc = 0; fc < 4; ++fc) acc[frg][fc] = (f32x4){0.f, 0.f, 0.f, 0.f};

#pragma unroll
        for (int kb = 0; kb < 12; ++kb) {
            __syncthreads();   // publish buf(kb&1); prior readers of buf^(1) done
            // prefetch next B tile into registers (flies across compute)
            const int nct = (kb == 11) ? ct + 1 : ct;
            const int nkb = (kb == 11) ? 0 : kb + 1;
            const bool has_next = !(ct == 15 && kb == 11);
            s16x8 p0, p1;
            if (has_next) {
                size_t gb = (size_t)(nct * 8 + KBP(nkb)) * 512;
                p0 = cbEp[gb + tid];
                p1 = cbEp[gb + 256 + tid];
            }
            // compute from buf(kb&1); A from registers (term: 0=hi,1=lo,2=hi)
            const int term = kb >> 2;
            const int c2k = kb & 3;
#pragma unroll
            for (int ks = 0; ks < 2; ++ks) {
                s16x8 b[4];
#pragma unroll
                for (int fc = 0; fc < 4; ++fc)
                    b[fc] = Bs[kb & 1][(fc * 2 + ks) * 64 + lane];
                const int ksb = c2k * 2 + ks;
#pragma unroll
                for (int fc = 0; fc < 4; ++fc)
#pragma unroll
                    for (int frg = 0; frg < 2; ++frg) {
                        s16x8 a = (term == 1) ? Al[frg][ksb] : Ah[frg][ksb];
                        acc[frg][fc] = mfma16(a, b[fc], acc[frg][fc]);
                    }
            }
            // write prefetched tile into the other buffer (vmcnt waits land here)
            if (has_next) {
                Bs[(kb + 1) & 1][tid] = p0;
                Bs[(kb + 1) & 1][256 + tid] = p1;
            }
        }
        // ---- argmin epilogue for this 64-col tile (ascending col, strict <) ----
#pragma unroll
        for (int fc = 0; fc < 4; ++fc) {
            int col = ct * 64 + fc * 16 + row16;
            float cn = cnorm[col];
#pragma unroll
            for (int frg = 0; frg < 2; ++frg)
#pragma unroll
                for (int reg = 0; reg < 4; ++reg) {
                    float val = fmaf(-2.f, acc[frg][fc][reg], cn);
                    if (val < minv[frg][reg]) { minv[frg][reg] = val; mini[frg][reg] = col; }
                }
        }
    }

    // butterfly over the 16-lane col group; tie -> lower index
#pragma unroll
    for (int mask = 1; mask <= 8; mask <<= 1) {
#pragma unroll
        for (int frg = 0; frg < 2; ++frg)
#pragma unroll
            for (int reg = 0; reg < 4; ++reg) {
                float ov = __shfl_xor(minv[frg][reg], mask, 64);
                int   oi = __shfl_xor(mini[frg][reg], mask, 64);
                if (ov < minv[frg][reg] ||
                    (ov == minv[frg][reg] && oi < mini[frg][reg])) {
                    minv[frg][reg] = ov; mini[frg][reg] = oi;
                }
            }
    }
    // rows are wave-private: direct write, no cross-wave reduction needed
    if (row16 == 0) {
#pragma unroll
        for (int frg = 0; frg < 2; ++frg)
#pragma unroll
            for (int reg = 0; reg < 4; ++reg)
                indices[r0 + w * 32 + frg * 16 + quad * 4 + reg] = mini[frg][reg];
    }
}

// ---------------------------------------------------------------------------
// ste (= quantized, exact fp32 codebook rows) + loss partials + histogram.
__global__ __launch_bounds__(256) void quantize_kernel(const float* __restrict__ x,
                                                       const float* __restrict__ cbT,
                                                       const int* __restrict__ indices,
                                                       float* __restrict__ ste,
                                                       int* __restrict__ counts,
                                                       float* __restrict__ loss_partial) {
    const int lane = threadIdx.x & 63;
    const int wid = (blockIdx.x * 256 + threadIdx.x) >> 6;   // global wave id
    const int nwaves = QBLOCKS * 4;

    float s = 0.f;
    for (int row = wid; row < N; row += nwaves) {
        const int k = indices[row];
        float4 q  = *(const float4*)&cbT[(size_t)k * D + lane * 4];   // L2-resident
        float4 xi = *(const float4*)&x[(size_t)row * D + lane * 4];
        *(float4*)&ste[(size_t)row * D + lane * 4] = q;
        float dx = q.x - xi.x, dy = q.y - xi.y, dz = q.z - xi.z, dw = q.w - xi.w;
        s = fmaf(dx, dx, s); s = fmaf(dy, dy, s);
        s = fmaf(dz, dz, s); s = fmaf(dw, dw, s);
        if (lane == 0) atomicAdd(&counts[k], 1);    // 1024-way spread
    }
#pragma unroll
    for (int off = 32; off >= 1; off >>= 1) s += __shfl_down(s, off, 64);
    __shared__ float red[4];
    if (lane == 0) red[threadIdx.x >> 6] = s;
    __syncthreads();
    if (threadIdx.x == 0)
        loss_partial[blockIdx.x] = red[0] + red[1] + red[2] + red[3];
}

// ---------------------------------------------------------------------------
// Single block: EMA cluster stats, perplexity, loss finalize, prefix-sum, cursor
__global__ __launch_bounds__(1024) void finalize_kernel(const int* __restrict__ counts,
                                                        const float* __restrict__ ema_c,
                                                        const int* __restrict__ counter,
                                                        const float* __restrict__ loss_partial,
                                                        float* __restrict__ out_perp,
                                                        float* __restrict__ out_loss,
                                                        int* __restrict__ offsets,
                                                        int* __restrict__ cursor,
                                                        float* __restrict__ smoothed) {
    const int k = threadIdx.x;
    __shared__ float fred[1024];
    __shared__ int scan[1024];
    __shared__ float nsum_s;
    __shared__ float ent_s;

    const int c = counts[k];
    const float bias = 1.0f - powf(GAMMA, (float)counter[0]);
    const float hid = fmaf(ema_c[k], GAMMA, (float)c * (1.0f - GAMMA));
    const float avg = hid / bias;

    fred[k] = avg;
    __syncthreads();
    for (int s = 512; s >= 1; s >>= 1) {
        if (k < s) fred[k] += fred[k + s];
        __syncthreads();
    }
    if (k == 0) nsum_s = fred[0];
    __syncthreads();
    const float nsum = nsum_s;

    float p = (float)c * (1.0f / (float)N);
    fred[k] = p * logf(p + 1e-10f);
    __syncthreads();
    for (int s = 512; s >= 1; s >>= 1) {
        if (k < s) fred[k] += fred[k + s];
        __syncthreads();
    }
    if (k == 0) ent_s = fred[0];
    __syncthreads();

    fred[k] = (k < QBLOCKS) ? loss_partial[k] : 0.f;
    __syncthreads();
    for (int s = 512; s >= 1; s >>= 1) {
        if (k < s) fred[k] += fred[k + s];
        __syncthreads();
    }

    scan[k] = c;
    __syncthreads();
    for (int s = 1; s < 1024; s <<= 1) {
        int v = (k >= s) ? scan[k - s] : 0;
        __syncthreads();
        scan[k] += v;
        __syncthreads();
    }
    const int excl = scan[k] - c;
    offsets[k] = excl;
    cursor[k] = excl;

    smoothed[k] = (avg + EPS) / (nsum + (float)K * EPS) * nsum;

    if (k == 0) {
        out_perp[0] = expf(-ent_s);
        out_loss[0] = BETA * fred[0] * (1.0f / ((float)N * (float)D));
    }
}

// Build permutation: rows grouped by cluster
__global__ __launch_bounds__(256) void scatter_kernel(const int* __restrict__ indices,
                                                      int* __restrict__ cursor,
                                                      int* __restrict__ perm) {
    const int n = blockIdx.x * 256 + threadIdx.x;
    const int k = indices[n];
    const int pos = atomicAdd(&cursor[k], 1);
    perm[pos] = n;
}

// ---------------------------------------------------------------------------
// dw[:,k] = sum of member rows; new_codebook = ((ema_dw*g + dw*(1-g))/bias)/smoothed
__global__ __launch_bounds__(256) void dw_codebook_kernel(const float* __restrict__ x,
                                                          const int* __restrict__ perm,
                                                          const int* __restrict__ offsets,
                                                          const int* __restrict__ counts,
                                                          const float* __restrict__ ema_dw,
                                                          const float* __restrict__ smoothed,
                                                          const int* __restrict__ counter,
                                                          float* __restrict__ out_cb) {
    const int k = blockIdx.x;
    const int d = threadIdx.x;
    const int off = offsets[k];
    const int cnt = counts[k];
    float acc = 0.f;
    int i = 0;
    for (; i + 4 <= cnt; i += 4) {
        int n0 = perm[off + i + 0];
        int n1 = perm[off + i + 1];
        int n2 = perm[off + i + 2];
        int n3 = perm[off + i + 3];
        acc += x[(size_t)n0 * D + d] + x[(size_t)n1 * D + d]
             + x[(size_t)n2 * D + d] + x[(size_t)n3 * D + d];
    }
    for (; i < cnt; ++i) acc += x[(size_t)perm[off + i] * D + d];
    const float bias = 1.0f - powf(GAMMA, (float)counter[0]);
    const float hid = fmaf(ema_dw[d * K + k], GAMMA, acc * (1.0f - GAMMA));
    out_cb[d * K + k] = (hid / bias) / smoothed[k];
}

// ---------------------------------------------------------------------------
extern "C" void kernel_launch(void* const* d_in, const int* in_sizes, int n_in,
                              void* d_out, int out_size, void* d_ws, size_t ws_size,
                              hipStream_t stream) {
    const float* x       = (const float*)d_in[0];  // [N, D]
    const float* cb      = (const float*)d_in[1];  // [D, K]
    const float* ema_c   = (const float*)d_in[2];  // [K]
    const float* ema_dw  = (const float*)d_in[3];  // [D, K]
    const int*   counter = (const int*)d_in[4];

    float* out = (float*)d_out;
    float* ste = out;                        // N*D
    float* out_perp = out + (size_t)N * D;   // 1
    float* out_loss = out_perp + 1;          // 1
    float* out_cb = out_perp + 2;            // D*K

    char* ws = (char*)d_ws;
    int* indices  = (int*)(ws + OFF_INDICES);
    int* perm     = (int*)(ws + OFF_PERM);
    int* counts   = (int*)(ws + OFF_COUNTS);
    float* cnorm  = (float*)(ws + OFF_CNORM);
    int* offsets  = (int*)(ws + OFF_OFFSETS);
    int* cursor   = (int*)(ws + OFF_CURSOR);
    float* smooth = (float*)(ws + OFF_SMOOTH);
    float* lossp  = (float*)(ws + OFF_LOSSP);
    float* cbT    = (float*)(ws + OFF_CBT);
    s16x8* cbEp   = (s16x8*)(ws + OFF_CBE);

    // zero counts + cnorm (contiguous 8 KB)
    hipMemsetAsync(counts, 0, 2 * K * sizeof(int), stream);

    pack_cb<<<64, 256, 0, stream>>>(cb, cbT, cbEp, cnorm);
    argmin_mfma_kernel<<<N / 128, 256, 0, stream>>>(x, cbEp, cnorm, indices);
    quantize_kernel<<<QBLOCKS, 256, 0, stream>>>(x, cbT, indices, ste, counts, lossp);
    finalize_kernel<<<1, 1024, 0, stream>>>(counts, ema_c, counter, lossp,
                                            out_perp, out_loss, offsets, cursor, smooth);
    scatter_kernel<<<N / 256, 256, 0, stream>>>(indices, cursor, perm);
    dw_codebook_kernel<<<K, 256, 0, stream>>>(x, perm, offsets, counts, ema_dw,
                                              smooth, counter, out_cb);
}